// Round 2
// baseline (1301.637 us; speedup 1.0000x reference)
//
#include <hip/hip_runtime.h>
#include <math.h>

#define WAYS 5
#define NQN 4096
#define NBATCH (NQN*WAYS)

// workspace float offsets
#define WS_SC 0         // 5*25*64 spt centered*rinv (l2-normalized) [w][i][c]
#define WS_RS 8000      // 125 inv l2 norms
#define WS_SP 8125      // 125 proj
#define WS_QM 8250      // 102400 qry per-token channel mean [q][j]
#define WS_QR 110650    // 102400 qry inv l2 norm
#define WS_TP 213050    // 102400 qry proj

// wave-level phase fence: DS ops of one wave complete in order; waitcnt + compiler barrier
#define WSYNC() do { asm volatile("s_waitcnt lgkmcnt(0)" ::: "memory"); __builtin_amdgcn_wave_barrier(); } while(0)

__global__ void prep_spt(const float* __restrict__ spt, const float* __restrict__ proj_w,
                         const float* __restrict__ proj_b, float* __restrict__ ws) {
    int tid = threadIdx.x;
    if (tid >= 125) return;
    int w = tid / 25, i = tid % 25;
    const float* base = spt + w * 1600 + i;
    float s = 0.f;
    for (int c = 0; c < 64; c++) s += base[c * 25];
    float m = s * (1.f / 64.f);
    float ss = 0.f, pj = 0.f;
    for (int c = 0; c < 64; c++) {
        float v = base[c * 25] - m;
        ss += v * v; pj += v * proj_w[c];
    }
    float rinv = rsqrtf(ss + 1e-6f);
    for (int c = 0; c < 64; c++)
        ws[WS_SC + (w * 25 + i) * 64 + c] = (base[c * 25] - m) * rinv;
    ws[WS_RS + w * 25 + i] = rinv;
    ws[WS_SP + w * 25 + i] = pj + proj_b[0];
}

__global__ void prep_qry(const float* __restrict__ qry, const float* __restrict__ proj_w,
                         const float* __restrict__ proj_b, float* __restrict__ ws) {
    int idx = blockIdx.x * 256 + threadIdx.x;
    if (idx >= NQN * 25) return;
    int q = idx / 25, j = idx % 25;
    const float* base = qry + q * 1600 + j;
    float s = 0.f;
    for (int c = 0; c < 64; c++) s += base[c * 25];
    float m = s * (1.f / 64.f);
    float ss = 0.f, pj = 0.f;
    for (int c = 0; c < 64; c++) {
        float v = base[c * 25] - m;
        ss += v * v; pj += v * proj_w[c];
    }
    ws[WS_QM + idx] = m;
    ws[WS_QR + idx] = rsqrtf(ss + 1e-6f);
    ws[WS_TP + idx] = pj + proj_b[0];
}

// Wave-level tiled matmul: O[m*SO+n] {=|+=} act( sum_k A[m*SA+k]*W[n*WN+k] + bias[n] )
// Tiles iterated by 64 lanes; if the leftover tile-set is <= 64 scalar outputs it is
// handled one-output-per-lane (avoids a nearly-empty extra tile round).
template<int M, int N, int K, int TM, int TN, int SA, int WN, int SO, int VW,
         bool ADD, bool GELU>
__device__ __forceinline__ void mmw(const float* __restrict__ A, const float* __restrict__ W,
                                    const float* __restrict__ bias, float* __restrict__ O,
                                    int lane) {
    static_assert(M % TM == 0 && N % TN == 0, "tile");
    static_assert(K % VW == 0, "vec");
    constexpr int GM = M / TM, GN = N / TN, ITEMS = GM * GN;
    constexpr int FULL = (ITEMS / 64) * 64;
    constexpr int REMO = (ITEMS - FULL) * TM * TN;
    constexpr bool SCT = (ITEMS > FULL) && (REMO <= 64);
    constexpr int LIM = SCT ? FULL : ITEMS;

    for (int v = lane; v < LIM; v += 64) {
        const int m0 = (v / GN) * TM, n0 = (v % GN) * TN;
        float acc[TM][TN];
#pragma unroll
        for (int a = 0; a < TM; a++)
#pragma unroll
            for (int c = 0; c < TN; c++) acc[a][c] = 0.f;

        if constexpr (VW == 4) {
#pragma unroll
            for (int k = 0; k < K; k += 4) {
                float4 av[TM], wv[TN];
#pragma unroll
                for (int a = 0; a < TM; a++) av[a] = *(const float4*)(A + (m0 + a) * SA + k);
#pragma unroll
                for (int c = 0; c < TN; c++) wv[c] = *(const float4*)(W + (n0 + c) * WN + k);
#pragma unroll
                for (int a = 0; a < TM; a++)
#pragma unroll
                    for (int c = 0; c < TN; c++) {
                        acc[a][c] += av[a].x * wv[c].x;
                        acc[a][c] += av[a].y * wv[c].y;
                        acc[a][c] += av[a].z * wv[c].z;
                        acc[a][c] += av[a].w * wv[c].w;
                    }
            }
        } else {
#pragma unroll 4
            for (int k = 0; k < K; k += 2) {
                float2 av[TM], wv[TN];
#pragma unroll
                for (int a = 0; a < TM; a++) av[a] = *(const float2*)(A + (m0 + a) * SA + k);
#pragma unroll
                for (int c = 0; c < TN; c++) wv[c] = *(const float2*)(W + (n0 + c) * WN + k);
#pragma unroll
                for (int a = 0; a < TM; a++)
#pragma unroll
                    for (int c = 0; c < TN; c++) {
                        acc[a][c] += av[a].x * wv[c].x;
                        acc[a][c] += av[a].y * wv[c].y;
                    }
            }
        }
#pragma unroll
        for (int a = 0; a < TM; a++)
#pragma unroll
            for (int c = 0; c < TN; c++) {
                int n = n0 + c;
                float r = acc[a][c] + (bias ? bias[n] : 0.f);
                if (GELU) r = 0.5f * r * (1.f + erff(r * 0.70710678118654752f));
                if (ADD) O[(m0 + a) * SO + n] += r; else O[(m0 + a) * SO + n] = r;
            }
    }
    if constexpr (SCT) {
        if (lane < REMO) {
            const int t = FULL + lane / (TM * TN), r0 = lane % (TM * TN);
            const int m = (t / GN) * TM + r0 / TN, n = (t % GN) * TN + r0 % TN;
            float acc = 0.f;
#pragma unroll 4
            for (int k = 0; k < K; k += 2) {
                float2 a2 = *(const float2*)(A + m * SA + k);
                float2 w2 = *(const float2*)(W + n * WN + k);
                acc += a2.x * w2.x;
                acc += a2.y * w2.y;
            }
            float r = acc + (bias ? bias[n] : 0.f);
            if (GELU) r = 0.5f * r * (1.f + erff(r * 0.70710678118654752f));
            if (ADD) O[m * SO + n] += r; else O[m * SO + n] = r;
        }
    }
}

__device__ __forceinline__ void ln_row(const float* __restrict__ x, float* __restrict__ h,
                                       const float* __restrict__ g, const float* __restrict__ bb) {
    float s = 0.f;
#pragma unroll
    for (int e = 0; e < 26; e++) s += x[e];
    float m = s * (1.f / 26.f);
    float vv = 0.f;
#pragma unroll
    for (int e = 0; e < 26; e++) { float d = x[e] - m; vv += d * d; }
    float r = rsqrtf(vv * (1.f / 26.f) + 1e-6f);
#pragma unroll
    for (int e = 0; e < 26; e++) h[e] = (x[e] - m) * r * g[e] + bb[e];
}

// One wavefront per (q,w) item. Per-wave LDS region (4096 floats):
//   xm 0..650 | hm 650..1300 (oatt / ln out / asv,aqv at end) | corrm 1300..1925
//   sm 1925..1989 (qm[0..24], qr[32..56]) | scr 1992..4096 (2104 floats, phase union:
//     tcb[25][68]=1700 | qkv[25][84]=2100 (q@0,k@28,v@56; heads at +h*13) |
//     mlp-hid[25][52]=1300 | dec 625 | qt 1600)
__global__ void __launch_bounds__(256, 2)
fused_kernel(const float* __restrict__ qry, const float* __restrict__ ws,
             const float* __restrict__ pos_x, const float* __restrict__ pos_y,
             const float* __restrict__ qkv_w, const float* __restrict__ qkv_b,
             const float* __restrict__ attn_w, const float* __restrict__ attn_b,
             const float* __restrict__ ln1_g, const float* __restrict__ ln1_b,
             const float* __restrict__ ln2_g, const float* __restrict__ ln2_b,
             const float* __restrict__ fc1_w, const float* __restrict__ fc1_b,
             const float* __restrict__ fc2_w, const float* __restrict__ fc2_b,
             const float* __restrict__ dec_w, const float* __restrict__ dec_b,
             float* __restrict__ out) {
    __shared__ __align__(16) float lds[4][4096];
    const int wid = threadIdx.x >> 6, lane = threadIdx.x & 63;
    const int b = blockIdx.x * 4 + wid, q = b / WAYS, w = b % WAYS;

    float* xm    = lds[wid];
    float* hm    = xm + 650;
    float* corrm = xm + 1300;
    float* sm    = xm + 1925;
    float* scr   = xm + 1992;

    // stage qm/qr for this q
    if (lane < 25) {
        sm[lane]      = ws[WS_QM + q * 25 + lane];
        sm[32 + lane] = ws[WS_QR + q * 25 + lane];
    }
    WSYNC();

    // stage tcb = l2-normalized qry tokens, [j][68]
    for (int e = lane; e < 1600; e += 64) {
        int c = e / 25, j = e - c * 25;
        scr[j * 68 + c] = (qry[q * 1600 + e] - sm[j]) * sm[32 + j];
    }
    WSYNC();

    // corr[i][j] = sn_i . tn_j  (A from global ws, L1-resident 32KB)
    mmw<25, 25, 64, 5, 1, 64, 68, 25, 4, false, false>(ws + WS_SC + w * 1600, scr, nullptr, corrm, lane);
    WSYNC();

    // x1: rows = qry tokens; [corr^T | tp] + pos
    for (int e = lane; e < 650; e += 64) {
        int t = e / 26, d = e - t * 26;
        float p = (d < 13) ? pos_x[(t % 5) * 13 + d] : pos_y[(t / 5) * 13 + (d - 13)];
        float base = (d < 25) ? corrm[d * 25 + t] : ws[WS_TP + q * 25 + t];
        xm[e] = base + p;
    }
    WSYNC();

    for (int it = 0; it < 2; ++it) {
        // ln1
        if (lane < 25) ln_row(xm + lane * 26, hm + lane * 26, ln1_g, ln1_b);
        WSYNC();
        // qkv as 3 contiguous 26-wide sections into scr, row stride 84: q@0, k@28, v@56.
        // Within a section, head h occupies [h*13, h*13+13).
        mmw<25, 26, 26, 5, 2, 26, 26, 84, 2, false, false>(hm, qkv_w,        qkv_b,      scr,      lane);
        mmw<25, 26, 26, 5, 2, 26, 26, 84, 2, false, false>(hm, qkv_w + 676,  qkv_b + 26, scr + 28, lane);
        mmw<25, 26, 26, 5, 2, 26, 26, 84, 2, false, false>(hm, qkv_w + 1352, qkv_b + 52, scr + 56, lane);
        WSYNC();
        // fused attention: lane (h,i) owns one score row entirely in registers.
        // Scalar LDS reads: head 1 starts at odd float offset (no 8B alignment), and
        // all 25 lanes of a head read the same k/v row address -> LDS broadcast, free.
        if (lane < 50) {
            int h = lane / 25, i = lane - h * 25;
            const float* qb = scr + i * 84 + h * 13;
            float qv[13];
#pragma unroll
            for (int k = 0; k < 13; k++) qv[k] = qb[k];
            float P[25];
            float mx = -1e30f;
#pragma unroll
            for (int j = 0; j < 25; j++) {
                const float* kb = scr + j * 84 + 28 + h * 13;
                float a = 0.f;
#pragma unroll
                for (int k = 0; k < 13; k++) a += qv[k] * kb[k];
                a *= 0.27735009811261457f;   // 13^-0.5
                P[j] = a; mx = fmaxf(mx, a);
            }
            float s = 0.f;
#pragma unroll
            for (int j = 0; j < 25; j++) { P[j] = __expf(P[j] - mx); s += P[j]; }
            float inv = 1.f / s;
            float o[13];
#pragma unroll
            for (int n = 0; n < 13; n++) o[n] = 0.f;
#pragma unroll
            for (int k = 0; k < 25; k++) {
                const float* vb = scr + k * 84 + 56 + h * 13;
                float p = P[k];
#pragma unroll
                for (int n = 0; n < 13; n++) o[n] += p * vb[n];
            }
            float* ob = hm + i * 26 + h * 13;
#pragma unroll
            for (int n = 0; n < 13; n++) ob[n] = o[n] * inv;
        }
        WSYNC();
        // attn proj + residual
        mmw<25, 26, 26, 5, 2, 26, 26, 26, 2, true, false>(hm, attn_w, attn_b, xm, lane);
        WSYNC();
        if (lane < 25) ln_row(xm + lane * 26, hm + lane * 26, ln2_g, ln2_b);
        WSYNC();
        // MLP in two 52-wide halves (keeps hidden in 1300 floats of scr)
        mmw<25, 52, 26, 5, 4, 26, 26, 52, 2, false, true>(hm, fc1_w, fc1_b, scr, lane);
        WSYNC();
        mmw<25, 26, 52, 5, 2, 52, 104, 26, 2, true, false>(scr, fc2_w, fc2_b, xm, lane);
        WSYNC();
        mmw<25, 52, 26, 5, 4, 26, 26, 52, 2, false, true>(hm, fc1_w + 1352, fc1_b + 52, scr, lane);
        WSYNC();
        mmw<25, 26, 52, 5, 2, 52, 104, 26, 2, true, false>(scr, fc2_w + 52, nullptr, xm, lane);
        WSYNC();
        // dec
        mmw<25, 25, 26, 5, 1, 26, 26, 25, 2, false, false>(xm, dec_w, dec_b, scr, lane);
        WSYNC();
        if (it == 0) {
            // x2: rows = spt tokens; [dec1^T + corr | sp] + pos
            for (int e = lane; e < 650; e += 64) {
                int t = e / 26, d = e - t * 26;
                float p = (d < 13) ? pos_x[(t % 5) * 13 + d] : pos_y[(t / 5) * 13 + (d - 13)];
                float base = (d < 25) ? (scr[d * 25 + t] + corrm[t * 25 + d]) : ws[WS_SP + w * 25 + t];
                xm[e] = base + p;
            }
            WSYNC();
        }
    }

    // refined = dec2 + corr (in scr)
    for (int e = lane; e < 625; e += 64) scr[e] += corrm[e];
    WSYNC();

    // attn_s: per column j, gnorm+softmax over i -> corrm
    if (lane < 25) {
        int j = lane;
        float s = 0.f;
        for (int i = 0; i < 25; i++) s += scr[i * 25 + j];
        float m = s * 0.04f;
        float ss = 0.f;
        for (int i = 0; i < 25; i++) { float d = scr[i * 25 + j] - m; ss += d * d; }
        float rinv = rsqrtf(ss * (1.f / 24.f) + 1e-5f) * 0.2f;   // /T_ATTN
        float mx = -1e30f;
        for (int i = 0; i < 25; i++) { float z = (scr[i * 25 + j] - m) * rinv; corrm[i * 25 + j] = z; mx = fmaxf(mx, z); }
        float se = 0.f;
        for (int i = 0; i < 25; i++) { float e2 = __expf(corrm[i * 25 + j] - mx); corrm[i * 25 + j] = e2; se += e2; }
        float inv = 1.f / se;
        for (int i = 0; i < 25; i++) corrm[i * 25 + j] *= inv;
    }
    WSYNC();
    if (lane < 25) {
        int i = lane; float s = 0.f;
        for (int j = 0; j < 25; j++) s += corrm[i * 25 + j];
        hm[i] = s * 0.04f / ws[WS_RS + w * 25 + i];              // asv
    }
    WSYNC();
    // attn_q: per row i, gnorm+softmax over j -> corrm
    if (lane < 25) {
        int i = lane;
        float s = 0.f;
        for (int j = 0; j < 25; j++) s += scr[i * 25 + j];
        float m = s * 0.04f;
        float ss = 0.f;
        for (int j = 0; j < 25; j++) { float d = scr[i * 25 + j] - m; ss += d * d; }
        float rinv = rsqrtf(ss * (1.f / 24.f) + 1e-5f) * 0.2f;
        float mx = -1e30f;
        for (int j = 0; j < 25; j++) { float z = (scr[i * 25 + j] - m) * rinv; corrm[i * 25 + j] = z; mx = fmaxf(mx, z); }
        float se = 0.f;
        for (int j = 0; j < 25; j++) { float e2 = __expf(corrm[i * 25 + j] - mx); corrm[i * 25 + j] = e2; se += e2; }
        float inv = 1.f / se;
        for (int j = 0; j < 25; j++) corrm[i * 25 + j] *= inv;
    }
    WSYNC();
    if (lane < 25) {
        int j = lane; float s = 0.f;
        for (int i = 0; i < 25; i++) s += corrm[i * 25 + j];
        hm[32 + j] = s * 0.04f / sm[32 + j];                     // aqv
    }
    WSYNC();

    // re-stage normalized qry transposed [c][25] into scr (refined is dead)
    for (int e = lane; e < 1600; e += 64) {
        int c = e / 25, j = e - c * 25;
        scr[e] = (qry[q * 1600 + e] - sm[j]) * sm[32 + j];
    }
    WSYNC();

    // pooled features per channel (lane = c) + cosine via butterfly reduce
    {
        float sv = 0.f, qv2 = 0.f;
        const float* snb = ws + WS_SC + w * 1600 + lane;
        for (int i = 0; i < 25; i++) sv  += hm[i]      * snb[i * 64];
        for (int j = 0; j < 25; j++) qv2 += hm[32 + j] * scr[lane * 25 + j];
        float d = sv * qv2, n1 = sv * sv, n2 = qv2 * qv2;
#pragma unroll
        for (int msk = 32; msk >= 1; msk >>= 1) {
            d  += __shfl_xor(d,  msk);
            n1 += __shfl_xor(n1, msk);
            n2 += __shfl_xor(n2, msk);
        }
        if (lane == 0) {
            n1 = fmaxf(sqrtf(n1), 1e-8f);
            n2 = fmaxf(sqrtf(n2), 1e-8f);
            out[b] = d / (n1 * n2) * 5.f;   // /TEMP
        }
    }
}

extern "C" void kernel_launch(void* const* d_in, const int* in_sizes, int n_in,
                              void* d_out, int out_size, void* d_ws, size_t ws_size,
                              hipStream_t stream) {
    const float* spt    = (const float*)d_in[0];
    const float* qry    = (const float*)d_in[1];
    const float* proj_w = (const float*)d_in[2];
    const float* proj_b = (const float*)d_in[3];
    const float* pos_x  = (const float*)d_in[4];
    const float* pos_y  = (const float*)d_in[5];
    const float* ln1_g  = (const float*)d_in[6];
    const float* ln1_b  = (const float*)d_in[7];
    const float* qkv_w  = (const float*)d_in[8];
    const float* qkv_b  = (const float*)d_in[9];
    const float* attn_w = (const float*)d_in[10];
    const float* attn_b = (const float*)d_in[11];
    const float* ln2_g  = (const float*)d_in[12];
    const float* ln2_b  = (const float*)d_in[13];
    const float* fc1_w  = (const float*)d_in[14];
    const float* fc1_b  = (const float*)d_in[15];
    const float* fc2_w  = (const float*)d_in[16];
    const float* fc2_b  = (const float*)d_in[17];
    const float* dec_w  = (const float*)d_in[18];
    const float* dec_b  = (const float*)d_in[19];
    float* ws  = (float*)d_ws;
    float* out = (float*)d_out;

    prep_spt<<<1, 128, 0, stream>>>(spt, proj_w, proj_b, ws);
    prep_qry<<<(NQN * 25 + 255) / 256, 256, 0, stream>>>(qry, proj_w, proj_b, ws);
    fused_kernel<<<NBATCH / 4, 256, 0, stream>>>(qry, ws, pos_x, pos_y, qkv_w, qkv_b, attn_w, attn_b,
                                                 ln1_g, ln1_b, ln2_g, ln2_b, fc1_w, fc1_b,
                                                 fc2_w, fc2_b, dec_w, dec_b, out);
}